// Round 17
// baseline (360.059 us; speedup 1.0000x reference)
//
#include <hip/hip_runtime.h>
#include <hip/hip_bf16.h>

#define NN 50000
#define NE 800000
#define SCAN_BS 1024
#define SCAN_NB ((NN + SCAN_BS - 1) / SCAN_BS)   // 49
#define EB ((NE + 255) / 256)                    // 3125 edge blocks
#define GB ((NN + 63) / 64)                      // 782 gemm blocks

typedef __attribute__((ext_vector_type(8))) __bf16 bf16x8;
typedef __attribute__((ext_vector_type(4))) float float4v;

__device__ __forceinline__ unsigned pack_bf2(float lo, float hi) {
    union { __bf16 b; unsigned short u; } a, c;
    a.b = (__bf16)lo; c.b = (__bf16)hi;
    return (unsigned)a.u | ((unsigned)c.u << 16);
}
__device__ __forceinline__ float2 unpack_bf2(unsigned v) {
    union { unsigned short u; __bf16 b; } lo, hi;
    lo.u = (unsigned short)(v & 0xffff); hi.u = (unsigned short)(v >> 16);
    return make_float2((float)lo.b, (float)hi.b);
}

// ================= fused prep: hist (edges) + 3x convert_w (grid-partitioned) =================

__device__ __forceinline__ void convert_w_part(const float* __restrict__ Ws,
                                               const float* __restrict__ Wd,
                                               const float* __restrict__ Wl,
                                               __bf16* __restrict__ Wt, int K, int i)
{
    if (i >= 320 * K) return;
    int c = i / K, k = i % K;
    float v;
    if (c < 128)      v = Ws[k * 128 + c];
    else if (c < 256) v = Wd[k * 128 + (c - 128)];
    else              v = Wl[k * 64 + (c - 256)];
    Wt[i] = (__bf16)v;
}

__global__ void __launch_bounds__(256)
prep_kernel(const int* __restrict__ ei, int* __restrict__ deg, int* __restrict__ rank,
            const float* __restrict__ Ws1, const float* __restrict__ Wd1,
            const float* __restrict__ Wl1, __bf16* __restrict__ Wt1,
            const float* __restrict__ Ws2, const float* __restrict__ Wd2,
            const float* __restrict__ Wl2, __bf16* __restrict__ Wt2,
            const float* __restrict__ Ws3, const float* __restrict__ Wd3,
            const float* __restrict__ Wl3, __bf16* __restrict__ Wt3)
{
    int bi = blockIdx.x;
    if (bi < EB) {
        int e = bi * 256 + threadIdx.x;
        if (e < NE) rank[e] = atomicAdd(&deg[ei[NE + e]], 1);
    } else if (bi < EB + 160) {
        convert_w_part(Ws1, Wd1, Wl1, Wt1, 128, (bi - EB) * 256 + threadIdx.x);
    } else if (bi < EB + 240) {
        convert_w_part(Ws2, Wd2, Wl2, Wt2, 64, (bi - EB - 160) * 256 + threadIdx.x);
    } else {
        convert_w_part(Ws3, Wd3, Wl3, Wt3, 64, (bi - EB - 240) * 256 + threadIdx.x);
    }
}

// ============================ CSR scan (row computed inline downstream) ============================

__global__ void __launch_bounds__(SCAN_BS)
scan1_kernel(const int* __restrict__ deg, int* __restrict__ exl, int* __restrict__ bsum)
{
    __shared__ int sh[SCAN_BS];
    int t = threadIdx.x;
    int i = blockIdx.x * SCAN_BS + t;
    int v = (i < NN) ? deg[i] : 0;
    sh[t] = v;
    __syncthreads();
    for (int off = 1; off < SCAN_BS; off <<= 1) {
        int u = (t >= off) ? sh[t - off] : 0;
        __syncthreads();
        sh[t] += u;
        __syncthreads();
    }
    if (i < NN) exl[i] = sh[t] - v;
    if (t == SCAN_BS - 1) bsum[blockIdx.x] = sh[t];
}

__global__ void __launch_bounds__(64)
scan2_kernel(const int* __restrict__ bsum, int* __restrict__ boff)
{
    int l = threadIdx.x;
    int v = (l < SCAN_NB) ? bsum[l] : 0;
    int own = v;
    for (int off = 1; off < 64; off <<= 1) {
        int u = __shfl_up(v, off);
        if (l >= off) v += u;
    }
    if (l < SCAN_NB) boff[l] = v - own;
}

// ============================ MFMA node GEMM body (LDS-staged B, LDS-transposed stores) ============================

__device__ __forceinline__ bf16x8 load_af(const __bf16* p) { return *(const bf16x8*)p; }
__device__ __forceinline__ bf16x8 load_af(const float* p) {
    float4 u = *(const float4*)p;
    float4 v = *(const float4*)(p + 4);
    bf16x8 r;
    r[0] = (__bf16)u.x; r[1] = (__bf16)u.y; r[2] = (__bf16)u.z; r[3] = (__bf16)u.w;
    r[4] = (__bf16)v.x; r[5] = (__bf16)v.y; r[6] = (__bf16)v.z; r[7] = (__bf16)v.w;
    return r;
}

template <int K, typename TIN>
__device__ __forceinline__ void gemm_body(
    int bi, char* ldsW,
    const TIN* __restrict__ xin, const __bf16* __restrict__ Wt,
    const float* __restrict__ a_s, const float* __restrict__ a_d,
    unsigned* __restrict__ hsb, float* __restrict__ lin,
    float* __restrict__ als, float* __restrict__ ald)
{
    const int tid  = threadIdx.x;
    const int lane = tid & 63;
    const int wave = tid >> 6;
    const int l15 = lane & 15, quad = lane >> 4;
    const int nblk0 = bi * 64;
    const int n0 = nblk0 + wave * 16;
    const int nA = min(n0 + l15, NN - 1);

    bf16x8 afr[K / 32];
#pragma unroll
    for (int ks = 0; ks < K / 32; ++ks)
        afr[ks] = load_af(xin + (size_t)nA * K + ks * 32 + quad * 8);

    float4v acc[20];
#pragma unroll
    for (int t = 0; t < 20; ++t) acc[t] = (float4v){0.f, 0.f, 0.f, 0.f};

#pragma unroll
    for (int h = 0; h < K / 64; ++h) {
        uint4 tmp[10];
#pragma unroll
        for (int i = 0; i < 10; ++i) {
            int idx = i * 256 + tid;           // [0,2560)
            int r = idx >> 3, c = idx & 7;     // chunk c = 16B = 8 bf16
            tmp[i] = *(const uint4*)(Wt + (size_t)r * K + h * 64 + c * 8);
        }
        if (h) __syncthreads();
#pragma unroll
        for (int i = 0; i < 10; ++i) {
            int idx = i * 256 + tid;
            int r = idx >> 3, c = idx & 7;
            *(uint4*)&ldsW[r * 144 + c * 16] = tmp[i];
        }
        __syncthreads();

#pragma unroll
        for (int ksh = 0; ksh < 2; ++ksh) {
            int ks = h * 2 + ksh;
#pragma unroll
            for (int t = 0; t < 20; ++t) {
                bf16x8 bf = *(const bf16x8*)&ldsW[(t * 16 + l15) * 144 + (ksh * 4 + quad) * 16];
                acc[t] = __builtin_amdgcn_mfma_f32_16x16x32_bf16(afr[ks], bf, acc[t], 0, 0, 0);
            }
        }
    }

    // ---- fused als/ald reduce (registers + shuffles only) ----
    float s0[4], s1[4], d0[4], d1[4];
#pragma unroll
    for (int r = 0; r < 4; ++r) { s0[r] = 0.f; s1[r] = 0.f; d0[r] = 0.f; d1[r] = 0.f; }
#pragma unroll
    for (int t = 0; t < 4; ++t) {
        float as0 = a_s[t * 16 + l15];
        float as1 = a_s[64 + t * 16 + l15];
        float ad0 = a_d[t * 16 + l15];
        float ad1 = a_d[64 + t * 16 + l15];
#pragma unroll
        for (int r = 0; r < 4; ++r) {
            s0[r] += acc[t][r] * as0;
            s1[r] += acc[t + 4][r] * as1;
            d0[r] += acc[t + 8][r] * ad0;
            d1[r] += acc[t + 12][r] * ad1;
        }
    }
#pragma unroll
    for (int m = 1; m < 16; m <<= 1) {
#pragma unroll
        for (int r = 0; r < 4; ++r) {
            s0[r] += __shfl_xor(s0[r], m);
            s1[r] += __shfl_xor(s1[r], m);
            d0[r] += __shfl_xor(d0[r], m);
            d1[r] += __shfl_xor(d1[r], m);
        }
    }

    // ---- stage outputs in LDS, then line-complete coalesced global stores ----
    __syncthreads();
    unsigned* hs_l  = (unsigned*)ldsW;                 // [64][68]
    float*    lin_l = (float*)(ldsW + 64 * 68 * 4);    // [64][68]
    float*    al_l  = (float*)(ldsW + 2 * 64 * 68 * 4);// [4][64]

#pragma unroll
    for (int t = 0; t < 4; ++t) {
#pragma unroll
        for (int r = 0; r < 4; ++r) {
            int ln = wave * 16 + quad * 4 + r;
            hs_l[ln * 68 + t * 16 + l15] = pack_bf2(acc[t][r], acc[t + 4][r]);
            lin_l[ln * 68 + t * 16 + l15] = acc[t + 16][r];
        }
    }
    if (l15 == 0) {
#pragma unroll
        for (int r = 0; r < 4; ++r) {
            int ln = wave * 16 + quad * 4 + r;
            al_l[0 * 64 + ln] = s0[r];
            al_l[1 * 64 + ln] = s1[r];
            al_l[2 * 64 + ln] = d0[r];
            al_l[3 * 64 + ln] = d1[r];
        }
    }
    __syncthreads();

#pragma unroll
    for (int it = 0; it < 4; ++it) {
        int idx4 = it * 256 + tid;
        int ln = idx4 >> 4, c4 = idx4 & 15;
        int n = nblk0 + ln;
        if (n < NN) {
            *(uint4*)&hsb[(size_t)n * 64 + c4 * 4] =
                *(const uint4*)&hs_l[ln * 68 + c4 * 4];
            *(float4*)&lin[(size_t)n * 64 + c4 * 4] =
                *(const float4*)&lin_l[ln * 68 + c4 * 4];
        }
    }
    {
        int half = tid >> 7;
        int t2 = tid & 127;
        int ln = t2 >> 1, h = t2 & 1;
        int n = nblk0 + ln;
        if (n < NN) {
            float v = al_l[(half * 2 + h) * 64 + ln];
            if (half == 0) als[n * 2 + h] = v;
            else           ald[n * 2 + h] = v;
        }
    }
}

// layer-1 gemm fused with atomic-free scatter (independent work, same launch):
// blocks [0,GB) do the gemm, [GB,GB+EB) do scatter with inline row computation.
__global__ void __launch_bounds__(256)
gemm1_scatter_kernel(const float* __restrict__ x, const __bf16* __restrict__ Wt,
                     const float* __restrict__ a_s, const float* __restrict__ a_d,
                     unsigned* __restrict__ hsb, float* __restrict__ lin,
                     float* __restrict__ als, float* __restrict__ ald,
                     const int* __restrict__ ei, const int* __restrict__ rank,
                     const int* __restrict__ exl, const int* __restrict__ boff,
                     int* __restrict__ csr_src)
{
    __shared__ __align__(16) char ldsW[320 * 144];
    if (blockIdx.x < GB) {
        gemm_body<128, float>(blockIdx.x, ldsW, x, Wt, a_s, a_d, hsb, lin, als, ald);
    } else {
        int e = (blockIdx.x - GB) * 256 + threadIdx.x;
        if (e < NE) {
            int s = ei[e], d = ei[NE + e];
            int p = exl[d] + boff[d >> 10] + rank[e];
            csr_src[p] = s;
        }
    }
}

template <int K, typename TIN>
__global__ void __launch_bounds__(256)
mfma_gemm(const TIN* __restrict__ xin, const __bf16* __restrict__ Wt,
          const float* __restrict__ a_s, const float* __restrict__ a_d,
          unsigned* __restrict__ hsb, float* __restrict__ lin,
          float* __restrict__ als, float* __restrict__ ald)
{
    __shared__ __align__(16) char ldsW[320 * 144];
    gemm_body<K, TIN>(blockIdx.x, ldsW, xin, Wt, a_s, a_d, hsb, lin, als, ald);
}

// ============================ fused aggregate (quarter-wave per edge) ============================

__device__ __forceinline__ float2 edge_w(const float* __restrict__ als, int s,
                                         float ad0, float ad1)
{
    float2 al = *(const float2*)&als[s * 2];
    float e0 = al.x + ad0; e0 = (e0 >= 0.f) ? e0 : 0.2f * e0;
    float e1 = al.y + ad1; e1 = (e1 >= 0.f) ? e1 : 0.2f * e1;
    return make_float2(__expf(e0), __expf(e1));
}

__device__ __forceinline__ void store_q(float* p, float v0, float v1, float v2, float v3) {
    *(float4*)p = make_float4(v0, v1, v2, v3);
}
__device__ __forceinline__ void store_q(__bf16* p, float v0, float v1, float v2, float v3) {
    *(uint2*)p = make_uint2(pack_bf2(v0, v1), pack_bf2(v2, v3));
}

// Row bounds computed inline from exl/boff (scan3 deleted). lin/b/bl hoisted
// above the edge loop so their latency overlaps the gather loop.
template <typename TO>
__global__ void __launch_bounds__(256)
gat_aggregate(const int* __restrict__ exl, const int* __restrict__ boff,
              const int* __restrict__ csr_src,
              const float* __restrict__ als, const float* __restrict__ ald,
              const unsigned* __restrict__ hsb, const float* __restrict__ lin,
              const float* __restrict__ b, const float* __restrict__ bl,
              TO* __restrict__ out)
{
    int w = (blockIdx.x * 256 + threadIdx.x) >> 6;
    int lane = threadIdx.x & 63;
    int q = lane >> 4;
    int l15 = lane & 15;
    if (w >= NN) return;
    int p0 = exl[w] + boff[w >> 10];
    int p1 = (w + 1 < NN) ? (exl[w + 1] + boff[(w + 1) >> 10]) : NE;
    float ad0 = ald[w * 2 + 0];
    float ad1 = ald[w * 2 + 1];

    // prefetch epilogue operands (latency hides under the edge loop)
    int c0 = 4 * l15;
    float4 lv = *(const float4*)&lin[(size_t)w * 64 + c0];
    float4 bv = *(const float4*)&b[c0];
    float4 blv = *(const float4*)&bl[c0];

    float a0[4] = {0.f, 0.f, 0.f, 0.f};
    float a1[4] = {0.f, 0.f, 0.f, 0.f};
    float den0 = 0.f, den1 = 0.f;

    int p = p0 + q;
    for (; p + 12 < p1; p += 16) {
        int sA = csr_src[p];
        int sB = csr_src[p + 4];
        int sC = csr_src[p + 8];
        int sD = csr_src[p + 12];
        float2 eA = edge_w(als, sA, ad0, ad1);
        float2 eB = edge_w(als, sB, ad0, ad1);
        float2 eC = edge_w(als, sC, ad0, ad1);
        float2 eD = edge_w(als, sD, ad0, ad1);
        uint4 gA = *(const uint4*)&hsb[(size_t)sA * 64 + 4 * l15];
        uint4 gB = *(const uint4*)&hsb[(size_t)sB * 64 + 4 * l15];
        uint4 gC = *(const uint4*)&hsb[(size_t)sC * 64 + 4 * l15];
        uint4 gD = *(const uint4*)&hsb[(size_t)sD * 64 + 4 * l15];
        den0 += (eA.x + eB.x) + (eC.x + eD.x);
        den1 += (eA.y + eB.y) + (eC.y + eD.y);
        float2 h;
        h = unpack_bf2(gA.x); a0[0] += eA.x * h.x; a1[0] += eA.y * h.y;
        h = unpack_bf2(gA.y); a0[1] += eA.x * h.x; a1[1] += eA.y * h.y;
        h = unpack_bf2(gA.z); a0[2] += eA.x * h.x; a1[2] += eA.y * h.y;
        h = unpack_bf2(gA.w); a0[3] += eA.x * h.x; a1[3] += eA.y * h.y;
        h = unpack_bf2(gB.x); a0[0] += eB.x * h.x; a1[0] += eB.y * h.y;
        h = unpack_bf2(gB.y); a0[1] += eB.x * h.x; a1[1] += eB.y * h.y;
        h = unpack_bf2(gB.z); a0[2] += eB.x * h.x; a1[2] += eB.y * h.y;
        h = unpack_bf2(gB.w); a0[3] += eB.x * h.x; a1[3] += eB.y * h.y;
        h = unpack_bf2(gC.x); a0[0] += eC.x * h.x; a1[0] += eC.y * h.y;
        h = unpack_bf2(gC.y); a0[1] += eC.x * h.x; a1[1] += eC.y * h.y;
        h = unpack_bf2(gC.z); a0[2] += eC.x * h.x; a1[2] += eC.y * h.y;
        h = unpack_bf2(gC.w); a0[3] += eC.x * h.x; a1[3] += eC.y * h.y;
        h = unpack_bf2(gD.x); a0[0] += eD.x * h.x; a1[0] += eD.y * h.y;
        h = unpack_bf2(gD.y); a0[1] += eD.x * h.x; a1[1] += eD.y * h.y;
        h = unpack_bf2(gD.z); a0[2] += eD.x * h.x; a1[2] += eD.y * h.y;
        h = unpack_bf2(gD.w); a0[3] += eD.x * h.x; a1[3] += eD.y * h.y;
    }
    for (; p + 4 < p1; p += 8) {
        int sA = csr_src[p];
        int sB = csr_src[p + 4];
        float2 eA = edge_w(als, sA, ad0, ad1);
        float2 eB = edge_w(als, sB, ad0, ad1);
        uint4 gA = *(const uint4*)&hsb[(size_t)sA * 64 + 4 * l15];
        uint4 gB = *(const uint4*)&hsb[(size_t)sB * 64 + 4 * l15];
        den0 += eA.x + eB.x;
        den1 += eA.y + eB.y;
        float2 h;
        h = unpack_bf2(gA.x); a0[0] += eA.x * h.x; a1[0] += eA.y * h.y;
        h = unpack_bf2(gA.y); a0[1] += eA.x * h.x; a1[1] += eA.y * h.y;
        h = unpack_bf2(gA.z); a0[2] += eA.x * h.x; a1[2] += eA.y * h.y;
        h = unpack_bf2(gA.w); a0[3] += eA.x * h.x; a1[3] += eA.y * h.y;
        h = unpack_bf2(gB.x); a0[0] += eB.x * h.x; a1[0] += eB.y * h.y;
        h = unpack_bf2(gB.y); a0[1] += eB.x * h.x; a1[1] += eB.y * h.y;
        h = unpack_bf2(gB.z); a0[2] += eB.x * h.x; a1[2] += eB.y * h.y;
        h = unpack_bf2(gB.w); a0[3] += eB.x * h.x; a1[3] += eB.y * h.y;
    }
    for (; p < p1; p += 4) {
        int s = csr_src[p];
        float2 e = edge_w(als, s, ad0, ad1);
        uint4 g = *(const uint4*)&hsb[(size_t)s * 64 + 4 * l15];
        den0 += e.x; den1 += e.y;
        float2 h;
        h = unpack_bf2(g.x); a0[0] += e.x * h.x; a1[0] += e.y * h.y;
        h = unpack_bf2(g.y); a0[1] += e.x * h.x; a1[1] += e.y * h.y;
        h = unpack_bf2(g.z); a0[2] += e.x * h.x; a1[2] += e.y * h.y;
        h = unpack_bf2(g.w); a0[3] += e.x * h.x; a1[3] += e.y * h.y;
    }

#pragma unroll
    for (int i = 0; i < 4; ++i) {
        a0[i] += __shfl_xor(a0[i], 16); a0[i] += __shfl_xor(a0[i], 32);
        a1[i] += __shfl_xor(a1[i], 16); a1[i] += __shfl_xor(a1[i], 32);
    }
    den0 += __shfl_xor(den0, 16); den0 += __shfl_xor(den0, 32);
    den1 += __shfl_xor(den1, 16); den1 += __shfl_xor(den1, 32);

    if (q == 0) {
        float r0 = 1.f / (den0 + 1e-16f);
        float r1 = 1.f / (den1 + 1e-16f);
        float v0 = 0.5f * (a0[0] * r0 + a1[0] * r1) + bv.x + blv.x + lv.x;
        float v1 = 0.5f * (a0[1] * r0 + a1[1] * r1) + bv.y + blv.y + lv.y;
        float v2 = 0.5f * (a0[2] * r0 + a1[2] * r1) + bv.z + blv.z + lv.z;
        float v3 = 0.5f * (a0[3] * r0 + a1[3] * r1) + bv.w + blv.w + lv.w;
        store_q(&out[(size_t)w * 64 + c0],
                fmaxf(v0, 0.f), fmaxf(v1, 0.f), fmaxf(v2, 0.f), fmaxf(v3, 0.f));
    }
}

// ============================ launch ============================

extern "C" void kernel_launch(void* const* d_in, const int* in_sizes, int n_in,
                              void* d_out, int out_size, void* d_ws, size_t ws_size,
                              hipStream_t stream)
{
    const float* x  = (const float*)d_in[0];
    const int*   ei = (const int*)d_in[1];
    const float* Ws[3]; const float* Wd[3]; const float* As[3]; const float* Ad[3];
    const float* Bb[3]; const float* Wl[3]; const float* Bl[3];
    for (int l = 0; l < 3; ++l) {
        int base = 2 + 7 * l;
        Ws[l] = (const float*)d_in[base + 0];
        Wd[l] = (const float*)d_in[base + 1];
        As[l] = (const float*)d_in[base + 2];
        Ad[l] = (const float*)d_in[base + 3];
        Bb[l] = (const float*)d_in[base + 4];
        Wl[l] = (const float*)d_in[base + 5];
        Bl[l] = (const float*)d_in[base + 6];
    }

    float* ws = (float*)d_ws;
    unsigned* hsb = (unsigned*)ws;                   // NN*64 packed bf16x2
    float* lin  = (float*)(hsb + (size_t)NN * 64);   // NN*64 f32
    float* als  = lin + (size_t)NN * 64;             // NN*2
    float* ald  = als + (size_t)NN * 2;              // NN*2
    __bf16* hb  = (__bf16*)(ald + (size_t)NN * 2);   // NN*64 bf16
    __bf16* Wt1 = hb + (size_t)NN * 64;              // 320*128
    __bf16* Wt2 = Wt1 + 320 * 128;                   // 320*64
    __bf16* Wt3 = Wt2 + 320 * 64;                    // 320*64
    int* deg     = (int*)(Wt3 + 320 * 64);           // NN
    int* rank    = deg + NN;                         // NE
    int* exl     = rank + NE;                        // NN
    int* bsum    = exl + NN;                         // SCAN_NB
    int* boff    = bsum + SCAN_NB;                   // SCAN_NB
    int* csr_src = boff + SCAN_NB;                   // NE

    const int WB = (NN * 64 + 255) / 256;

    // --- CSR + prep ---
    hipMemsetAsync(deg, 0, sizeof(int) * NN, stream);
    prep_kernel<<<EB + 320, 256, 0, stream>>>(ei, deg, rank,
        Ws[0], Wd[0], Wl[0], Wt1,
        Ws[1], Wd[1], Wl[1], Wt2,
        Ws[2], Wd[2], Wl[2], Wt3);
    scan1_kernel<<<SCAN_NB, SCAN_BS, 0, stream>>>(deg, exl, bsum);
    scan2_kernel<<<1, 64, 0, stream>>>(bsum, boff);

    // --- layer 1 gemm fused with scatter (independent work overlapped) ---
    gemm1_scatter_kernel<<<GB + EB, 256, 0, stream>>>(
        x, Wt1, As[0], Ad[0], hsb, lin, als, ald, ei, rank, exl, boff, csr_src);

    for (int l = 0; l < 3; ++l) {
        if (l > 0) {
            const __bf16* wt = (l == 1) ? Wt2 : Wt3;
            mfma_gemm<64, __bf16><<<GB, 256, 0, stream>>>(
                hb, wt, As[l], Ad[l], hsb, lin, als, ald);
        }
        if (l == 2) {
            gat_aggregate<float><<<WB, 256, 0, stream>>>(
                exl, boff, csr_src, als, ald, hsb, lin, Bb[l], Bl[l], (float*)d_out);
        } else {
            gat_aggregate<__bf16><<<WB, 256, 0, stream>>>(
                exl, boff, csr_src, als, ald, hsb, lin, Bb[l], Bl[l], hb);
        }
    }
}